// Round 3
// baseline (360.477 us; speedup 1.0000x reference)
//
#include <hip/hip_runtime.h>

// FloodPath R6: wave-autonomous 64x256 windows, zero block barriers.
//   K1 (pack): unchanged — stream float2 [H][W][2] -> occ/flood bit planes.
//   K2 (flood): each wave owns a 64-row x 4-word (256-col) halo'd window in
//     registers (lane = row), word-aligned staging (no funnel shifts),
//     interior 32 rows x 128 cols => redundancy 4x (was 8x). 16 dilation
//     steps via shfl up/down + cross-word carries. Bit-sliced counters kept
//     only for the 2 interior words. The wave now owns its full interior
//     width, so transpose-plane and packed-output staging are WAVE-PRIVATE:
//     no __syncthreads anywhere — wave-synchronous LDS ordered by
//     s_waitcnt lgkmcnt(0). fc loads prefetched one row-pair ahead.
//     Packed dwordx4 output stores kept from R5 (fixed R4's 1.6x write
//     inflation: 315MB -> ~197MB).

typedef unsigned long long u64;

#define HH 4096
#define WW 4096
#define WPR 64            // u64 words per image row
#define NSTEPS 16
#define HALO 16
#define IT_R 32           // interior rows per wave
#define IT_C 128          // interior cols per wave (2 words)

// ---------------- Kernel 1: bitpack ----------------
__global__ __launch_bounds__(256) void pack_kernel(
    const float* __restrict__ flood_input,
    u64* __restrict__ occP, u64* __restrict__ flP)
{
    const int lane = threadIdx.x & 63;
    const int wv   = threadIdx.x >> 6;
    const int r    = blockIdx.x;                  // one image row per block
#pragma unroll
    for (int b = 0; b < 2; ++b) {
        float vx[8], vy[8];
#pragma unroll
        for (int j = 0; j < 8; ++j) {
            const int w = wv * 16 + b * 8 + j;
            const float2 v = *(const float2*)(flood_input +
                                ((size_t)r * WW + (w << 6) + lane) * 2);
            vx[j] = v.x; vy[j] = v.y;
        }
#pragma unroll
        for (int j = 0; j < 8; ++j) {
            const int w = wv * 16 + b * 8 + j;
            const u64 om = __ballot(vx[j] > 0.5f);
            const u64 fm = __ballot(vy[j] > 0.5f);
            if (lane == 0) {
                occP[(size_t)r * WPR + w] = om;
                flP [(size_t)r * WPR + w] = fm;
            }
        }
    }
}

// ---------------- Kernel 2: flood + count + output ----------------
__global__ __launch_bounds__(256, 4) void flood_kernel(
    const u64* __restrict__ occP, const u64* __restrict__ flP,
    const float* __restrict__ flood_count,
    float* __restrict__ out)
{
    // wave-private: interior rows x {occ1,occ2,f1,f2,cA0..4,cB0..4} (pad 15)
    __shared__ u64   plane[4][IT_R][15];          // 15360 B
    __shared__ float out2 [4][2 * IT_C * 3];      // 12288 B

    const int tid  = threadIdx.x;
    const int lane = tid & 63;
    const int wv   = tid >> 6;

    const int R0 = blockIdx.y * (4 * IT_R) + wv * IT_R;   // wave's interior rows
    const int C0 = blockIdx.x * IT_C;                     // wave's interior cols

    // ---- Stage: lane = window row (R0-16+lane); words w0..w0+3, aligned.
    const int gr   = R0 - HALO + lane;
    const bool rin = (gr >= 0) & (gr < HH);
    const size_t base = (size_t)(rin ? gr : 0) * WPR;
    const int w0 = (C0 >> 6) - 1;

    u64 occ[4], f[4];
#pragma unroll
    for (int k = 0; k < 4; ++k) {
        const int q  = w0 + k;
        const bool v = rin & (q >= 0) & (q < WPR);
        const int qc = min(max(q, 0), WPR - 1);
        const u64 o  = occP[base + qc];
        const u64 fl = flP [base + qc];
        occ[k] = v ? o  : ~0ull;                 // OOB => wall
        f[k]   = v ? fl : 0ull;                  // OOB => no flood
    }

    // ---- 16 dilation steps, registers only. Counters for interior words 1,2.
    u64 cA0=0,cA1=0,cA2=0,cA3=0,cA4=0;
    u64 cB0=0,cB1=0,cB2=0,cB3=0,cB4=0;
#pragma unroll
    for (int it = 0; it < NSTEPS; ++it) {
        u64 up0=__shfl_up(f[0],1),   up1=__shfl_up(f[1],1),
            up2=__shfl_up(f[2],1),   up3=__shfl_up(f[3],1);
        u64 dn0=__shfl_down(f[0],1), dn1=__shfl_down(f[1],1),
            dn2=__shfl_down(f[2],1), dn3=__shfl_down(f[3],1);
        if (lane == 0)  { up0=0; up1=0; up2=0; up3=0; }
        if (lane == 63) { dn0=0; dn1=0; dn2=0; dn3=0; }
        u64 nf0 = ~occ[0] & (f[0] | (f[0]<<1)               | (f[0]>>1) | (f[1]<<63) | up0 | dn0);
        u64 nf1 = ~occ[1] & (f[1] | (f[1]<<1) | (f[0]>>63)  | (f[1]>>1) | (f[2]<<63) | up1 | dn1);
        u64 nf2 = ~occ[2] & (f[2] | (f[2]<<1) | (f[1]>>63)  | (f[2]>>1) | (f[3]<<63) | up2 | dn2);
        u64 nf3 = ~occ[3] & (f[3] | (f[3]<<1) | (f[2]>>63)  | (f[3]>>1)              | up3 | dn3);
        u64 c, t;
        c = nf1;
        t=cA0; cA0=t^c; c=t&c;  t=cA1; cA1=t^c; c=t&c;
        t=cA2; cA2=t^c; c=t&c;  t=cA3; cA3=t^c; c=t&c;  cA4^=c;
        c = nf2;
        t=cB0; cB0=t^c; c=t&c;  t=cB1; cB1=t^c; c=t&c;
        t=cB2; cB2=t^c; c=t&c;  t=cB3; cB3=t^c; c=t&c;  cB4^=c;
        f[0]=nf0; f[1]=nf1; f[2]=nf2; f[3]=nf3;
    }

    // ---- Wave-private transpose: lanes 16..47 hold interior rows.
    {
        const int ir = lane - HALO;
        if (ir >= 0 && ir < IT_R) {
            u64* p = plane[wv][ir];
            p[0]=occ[1]; p[1]=occ[2]; p[2]=f[1]; p[3]=f[2];
            p[4]=cA0; p[5]=cA1; p[6]=cA2; p[7]=cA3; p[8]=cA4;
            p[9]=cB0; p[10]=cB1; p[11]=cB2; p[12]=cB3; p[13]=cB4;
        }
    }
    asm volatile("s_waitcnt lgkmcnt(0)" ::: "memory");   // wave-sync LDS

    // ---- Output: 16 row-pairs per wave, fully wave-private, no barriers.
    const int half = lane >> 5;                  // 0 or 1: row within pair
    const int l32  = lane & 31;
    const int col0 = l32 * 4;                    // interior col of my 4 px
    const int word = col0 >> 6;                  // 0 or 1 (plane word sel)
    const int bit0 = col0 & 63;
    const float* fcbase = flood_count + (size_t)(R0 + half) * WW + C0 + col0;
    float* outw = out + ((size_t)R0 * WW + C0) * 3;

    float4 fnext = *(const float4*)fcbase;       // prefetch pair 0
    for (int t = 0; t < IT_R / 2; ++t) {
        const float4 fc4 = fnext;
        if (t + 1 < IT_R / 2)
            fnext = *(const float4*)(fcbase + (size_t)(t + 1) * 2 * WW);

        const int irow = t * 2 + half;
        const u64* p = plane[wv][irow];
        const u64 ow = p[word];
        const u64 fw = p[2 + word];
        const int cb = 4 + word * 5;
        const u64 k0 = p[cb+0], k1 = p[cb+1], k2 = p[cb+2],
                  k3 = p[cb+3], k4 = p[cb+4];

        float v[12];
        const float fcv[4] = { fc4.x, fc4.y, fc4.z, fc4.w };
#pragma unroll
        for (int j = 0; j < 4; ++j) {
            const int bit = bit0 + j;
            int cv = (int)((k0 >> bit) & 1ull)
                   + ((int)((k1 >> bit) & 1ull) << 1)
                   + ((int)((k2 >> bit) & 1ull) << 2)
                   + ((int)((k3 >> bit) & 1ull) << 3)
                   + ((int)((k4 >> bit) & 1ull) << 4);
            v[j*3+0] = (float)((ow >> bit) & 1ull);
            v[j*3+1] = (float)((fw >> bit) & 1ull);
            v[j*3+2] = (float)cv + fcv[j];
        }
        // stage contiguously: half*1536B + l32*48B (16B aligned)
        float* dst = &out2[wv][half * 384 + l32 * 12];
        *(float4*)(dst + 0) = make_float4(v[0], v[1], v[2],  v[3]);
        *(float4*)(dst + 4) = make_float4(v[4], v[5], v[6],  v[7]);
        *(float4*)(dst + 8) = make_float4(v[8], v[9], v[10], v[11]);

        asm volatile("s_waitcnt lgkmcnt(0)" ::: "memory");   // wave-sync LDS

        // read back linearly, 3 packed dwordx4 stores per lane
#pragma unroll
        for (int st = 0; st < 3; ++st) {
            const int L   = st * 256 + lane * 4;   // float idx in 768-float pair
            const int row = (L >= 384) ? 1 : 0;
            const int off = L - row * 384;
            const float4 q = *(const float4*)(&out2[wv][L]);
            *(float4*)(outw + ((size_t)(t * 2 + row) * WW) * 3 + off) = q;
        }
    }
}

extern "C" void kernel_launch(void* const* d_in, const int* in_sizes, int n_in,
                              void* d_out, int out_size, void* d_ws, size_t ws_size,
                              hipStream_t stream) {
    const float* flood_input = (const float*)d_in[0];  // [4096][4096][2]
    const float* flood_cnt   = (const float*)d_in[1];  // [4096][4096]
    float* out = (float*)d_out;                        // [4096][4096][3]

    u64* occP = (u64*)d_ws;                            // 2 MiB
    u64* flP  = occP + (size_t)HH * WPR;               // 2 MiB

    pack_kernel<<<dim3(HH), dim3(256), 0, stream>>>(flood_input, occP, flP);

    dim3 grid(WW / IT_C, HH / (4 * IT_R));             // 32 x 32 = 1024 blocks
    flood_kernel<<<grid, dim3(256), 0, stream>>>(occP, flP, flood_cnt, out);
}